// Round 3
// baseline (22993.245 us; speedup 1.0000x reference)
//
#include <hip/hip_runtime.h>
#include <math.h>

#define BB 8
#define TT 4096
#define DD 512
constexpr float LRF = 0.01f;

typedef float v2f __attribute__((ext_vector_type(2)));

// ---------------- workspace layout (floats) ----------------
// A  : [4096][512]   mean of x over batch
// CU : [4096][512]   c_s * u_s
// G  : [16][256][256] per-superchunk Gram of A
// P  : [256][512]    A_sc - A_sc @ W(p)^T (RMW'd by tm_sc forward corrections)
// W  : [512][512]    running W_base + W_c
// WS : [16][512][512] W snapshots at t = 256*p
// S  : [16][2048][256] attention scores
#define OFF_A  0
#define OFF_CU 2097152
#define OFF_G  4194304
#define OFF_P  5242880
#define OFF_BV 5373952
#define OFF_W  5406720
#define OFF_WS 5668864
#define OFF_S  9863168

__global__ void tm_mean(const float* __restrict__ x, float* __restrict__ a) {
    int idx = blockIdx.x * 256 + threadIdx.x;
    float s = 0.f;
#pragma unroll
    for (int b = 0; b < BB; ++b) s += x[b * (TT * DD) + idx];
    a[idx] = s * 0.125f;
}

__global__ void tm_init(const float* __restrict__ wb, const float* __restrict__ wc,
                        float* __restrict__ W, float* __restrict__ Wsnap) {
    int idx = blockIdx.x * 256 + threadIdx.x;
    float v = wb[idx] + wc[idx];
    W[idx] = v;
    Wsnap[idx] = v;
}

// G[p][s][t] = a_{p*256+s} . a_{p*256+t}; grid 256
__global__ __launch_bounds__(256) void tm_gram(const float* __restrict__ a, float* __restrict__ G) {
    __shared__ float sl[64 * 65];
    __shared__ float tl[64 * 65];
    int bid = blockIdx.x;
    int p = bid >> 4, ts = (bid >> 2) & 3, tt = bid & 3;
    int tid = threadIdx.x;
    int c0 = (tid & 15) * 4, r0 = (tid >> 4) * 4;
    float acc[4][4] = {};
    for (int kt = 0; kt < 8; ++kt) {
        if (kt) __syncthreads();
        for (int l = tid; l < 64 * 16; l += 256) {
            int r = l >> 4, c4 = (l & 15) * 4;
            float4 v = *(const float4*)&a[(p * 256 + ts * 64 + r) * DD + kt * 64 + c4];
            sl[r * 65 + c4] = v.x; sl[r * 65 + c4 + 1] = v.y;
            sl[r * 65 + c4 + 2] = v.z; sl[r * 65 + c4 + 3] = v.w;
            float4 u = *(const float4*)&a[(p * 256 + tt * 64 + r) * DD + kt * 64 + c4];
            tl[r * 65 + c4] = u.x; tl[r * 65 + c4 + 1] = u.y;
            tl[r * 65 + c4 + 2] = u.z; tl[r * 65 + c4 + 3] = u.w;
        }
        __syncthreads();
        for (int kk = 0; kk < 64; ++kk) {
            float as[4], at[4];
#pragma unroll
            for (int q = 0; q < 4; ++q) { as[q] = sl[(r0 + q) * 65 + kk]; at[q] = tl[(c0 + q) * 65 + kk]; }
#pragma unroll
            for (int q = 0; q < 4; ++q)
#pragma unroll
                for (int w2 = 0; w2 < 4; ++w2) acc[q][w2] += as[q] * at[w2];
        }
    }
#pragma unroll
    for (int q = 0; q < 4; ++q) {
        float4 v = make_float4(acc[q][0], acc[q][1], acc[q][2], acc[q][3]);
        *(float4*)&G[p * 65536 + (ts * 64 + r0 + q) * 256 + tt * 64 + c0] = v;
    }
}

// P[t][i] = a[p*256+t][i] - sum_j W[i][j] a[p*256+t][j]; grid 32
__global__ __launch_bounds__(256) void tm_P(const float* __restrict__ a, const float* __restrict__ W,
                                            float* __restrict__ P, int p) {
    __shared__ float al[64 * 65];
    __shared__ float wl[64 * 65];
    int bid = blockIdx.x;
    int bt = bid & 3, bi = bid >> 2;
    int tid = threadIdx.x;
    int c0 = (tid & 15) * 4, r0 = (tid >> 4) * 4;
    float acc[4][4] = {};
    for (int kt = 0; kt < 8; ++kt) {
        if (kt) __syncthreads();
        for (int l = tid; l < 64 * 16; l += 256) {
            int r = l >> 4, c4 = (l & 15) * 4;
            float4 v = *(const float4*)&a[(p * 256 + bt * 64 + r) * DD + kt * 64 + c4];
            al[r * 65 + c4] = v.x; al[r * 65 + c4 + 1] = v.y;
            al[r * 65 + c4 + 2] = v.z; al[r * 65 + c4 + 3] = v.w;
            float4 u = *(const float4*)&W[(bi * 64 + r) * DD + kt * 64 + c4];
            wl[r * 65 + c4] = u.x; wl[r * 65 + c4 + 1] = u.y;
            wl[r * 65 + c4 + 2] = u.z; wl[r * 65 + c4 + 3] = u.w;
        }
        __syncthreads();
        for (int kk = 0; kk < 64; ++kk) {
            float af[4], bf[4];
#pragma unroll
            for (int q = 0; q < 4; ++q) { af[q] = al[(r0 + q) * 65 + kk]; bf[q] = wl[(c0 + q) * 65 + kk]; }
#pragma unroll
            for (int q = 0; q < 4; ++q)
#pragma unroll
                for (int w2 = 0; w2 < 4; ++w2) acc[q][w2] += af[q] * bf[w2];
        }
    }
#pragma unroll
    for (int q = 0; q < 4; ++q) {
        float4 av = *(const float4*)&a[(p * 256 + bt * 64 + r0 + q) * DD + bi * 64 + c0];
        float4 v = make_float4(av.x - acc[q][0], av.y - acc[q][1],
                               av.z - acc[q][2], av.w - acc[q][3]);
        *(float4*)&P[(bt * 64 + r0 + q) * DD + bi * 64 + c0] = v;
    }
}

// ---- fused per-superchunk serial kernel: 1 block, 512 threads (thread = dim) ----
// For each of 4 chunks: sequential 64-step scan (norm -> clip -> rank-1 Gram update),
// then apply this chunk's corrections forward (next chunk in regs, later chunks via P RMW).
// All G reads are wave-uniform -> scalar loads, no LDS pipe pressure.
__global__ __launch_bounds__(512) void tm_sc(const float* __restrict__ G,
                                             float* __restrict__ P,
                                             float* __restrict__ cu, int p) {
    __shared__ float part[2][8];
    int tid = threadIdx.x;
    int wid = tid >> 6, lane = tid & 63;
    const float* Gp = G + p * 65536;
    float* cup = cu + p * 256 * DD;
    float b[64], y[64];
#pragma unroll
    for (int t = 0; t < 64; ++t) b[t] = P[t * DD + tid];

    for (int j = 0; j < 4; ++j) {
        const float* Gj = Gp + (j * 64) * 256;
        // ---- sequential scan, fully unrolled (static reg indices) ----
#pragma unroll
        for (int s = 0; s < 64; ++s) {
            float u = b[s];
            float v = u * u;
#pragma unroll
            for (int off = 32; off > 0; off >>= 1) v += __shfl_xor(v, off, 64);
            if (lane == 0) part[s & 1][wid] = v;
            __syncthreads();
            float n2u = 0.f;
#pragma unroll
            for (int w8 = 0; w8 < 8; ++w8) n2u += part[s & 1][w8];
            float n2 = n2u * Gj[s * 256 + j * 64 + s];          // ||u||^2 * ||a||^2
            float cs = (n2 > 0.25f) ? 0.5f * rsqrtf(n2) : 1.0f; // min(1, CLIP/n)
            float yv = cs * u;
            y[s] = yv;
            float w = LRF * yv;
            const float* gr = Gj + s * 256 + j * 64;
#pragma unroll
            for (int t = s + 1; t < 64; ++t) b[t] -= gr[t] * w;  // gr[t] uniform -> sgpr
        }
        // store y chunk (coalesced)
#pragma unroll
        for (int s2 = 0; s2 < 64; ++s2) cup[(j * 64 + s2) * DD + tid] = y[s2];

        if (j < 3) {
            // next chunk into regs, apply this chunk's correction
#pragma unroll
            for (int t = 0; t < 64; ++t) b[t] = P[((j + 1) * 64 + t) * DD + tid];
#pragma unroll
            for (int s = 0; s < 64; ++s) {
                float w = LRF * y[s];
                const float* gr = Gj + s * 256 + (j + 1) * 64;
#pragma unroll
                for (int t = 0; t < 64; ++t) b[t] -= gr[t] * w;
            }
            // farther chunks via global P RMW (t-tiled to cap VGPRs)
            for (int jf = j + 2; jf < 4; ++jf) {
                for (int tb = 0; tb < 4; ++tb) {
                    float acc[16];
#pragma unroll
                    for (int t = 0; t < 16; ++t) acc[t] = 0.f;
#pragma unroll
                    for (int s = 0; s < 64; ++s) {
                        const float* gr = Gj + s * 256 + jf * 64 + tb * 16;
                        float ys = y[s];
#pragma unroll
                        for (int t = 0; t < 16; ++t) acc[t] += gr[t] * ys;
                    }
#pragma unroll
                    for (int t = 0; t < 16; ++t) {
                        int row = (jf * 64 + tb * 16 + t) * DD + tid;
                        P[row] -= LRF * acc[t];
                    }
                }
            }
        }
    }
}

// W += LR * sum_{r in sc p} cu_r (x) a_r; optional snapshot / final output
__global__ void tm_wupd(const float* __restrict__ a, const float* __restrict__ cu,
                        float* __restrict__ W, float* __restrict__ Wsnap,
                        const float* __restrict__ wb, float* __restrict__ outW,
                        int p, int snap_p, int is_final) {
    int idx = blockIdx.x * 256 + threadIdx.x;
    int i = idx >> 9, jj = idx & 511;
    const float* cb = cu + p * 256 * DD + i;
    const float* ab = a + p * 256 * DD + jj;
    float s = 0.f;
#pragma unroll 8
    for (int r = 0; r < 256; ++r) s += cb[r * DD] * ab[r * DD];
    float w = W[idx] + LRF * s;
    W[idx] = w;
    if (snap_p >= 0) Wsnap[snap_p * DD * DD + idx] = w;
    if (is_final) outW[idx] = w - wb[idx];
}

// ---------------- phase 3 (parallel output), transposed-LDS b128 fragments ----------------

// out[b,t,:] = x[b,t,:] @ Wsnap[p].T
__global__ __launch_bounds__(256) void tm_mem(const float* __restrict__ x, const float* __restrict__ Wsnap,
                                              float* __restrict__ out) {
    __shared__ float al[64 * 68];
    __shared__ float bl[64 * 68];
    int bid = blockIdx.x;
    int pp = bid >> 8, rem = bid & 255, rt = rem >> 3, it = rem & 7;
    int tid = threadIdx.x;
    int c0 = (tid & 15) * 4, r0 = (tid >> 4) * 4;
    const float* Wp = Wsnap + pp * DD * DD;
    v2f acc[4][2] = {};
    for (int kt = 0; kt < 8; ++kt) {
        if (kt) __syncthreads();
        for (int l = tid; l < 64 * 16; l += 256) {
            int r = l >> 4, c4 = (l & 15) * 4;
            int rloc = rt * 64 + r;
            int grow = ((rloc >> 8) * TT) + pp * 256 + (rloc & 255);
            float4 v = *(const float4*)&x[grow * DD + kt * 64 + c4];
            al[(c4 + 0) * 68 + r] = v.x; al[(c4 + 1) * 68 + r] = v.y;
            al[(c4 + 2) * 68 + r] = v.z; al[(c4 + 3) * 68 + r] = v.w;
            float4 u = *(const float4*)&Wp[(it * 64 + r) * DD + kt * 64 + c4];
            bl[(c4 + 0) * 68 + r] = u.x; bl[(c4 + 1) * 68 + r] = u.y;
            bl[(c4 + 2) * 68 + r] = u.z; bl[(c4 + 3) * 68 + r] = u.w;
        }
        __syncthreads();
        for (int kk = 0; kk < 64; ++kk) {
            float4 a4 = *(const float4*)&al[kk * 68 + r0];
            float4 b4 = *(const float4*)&bl[kk * 68 + c0];
            v2f blo = {b4.x, b4.y}, bhi = {b4.z, b4.w};
            float af[4] = {a4.x, a4.y, a4.z, a4.w};
#pragma unroll
            for (int q = 0; q < 4; ++q) { acc[q][0] += af[q] * blo; acc[q][1] += af[q] * bhi; }
        }
    }
#pragma unroll
    for (int q = 0; q < 4; ++q) {
        int rloc = rt * 64 + r0 + q;
        int grow = ((rloc >> 8) * TT) + pp * 256 + (rloc & 255);
        float4 v = make_float4(acc[q][0][0], acc[q][0][1], acc[q][1][0], acc[q][1][1]);
        *(float4*)&out[grow * DD + it * 64 + c0] = v;
    }
}

// S[p][rloc][s] = x[row] . a[p*256+s]
__global__ __launch_bounds__(256) void tm_score(const float* __restrict__ x, const float* __restrict__ a,
                                                float* __restrict__ S) {
    __shared__ float al[64 * 68];
    __shared__ float bl[64 * 68];
    int bid = blockIdx.x;
    int st = bid & 3, rt = (bid >> 2) & 31, pp = bid >> 7;
    int tid = threadIdx.x;
    int c0 = (tid & 15) * 4, r0 = (tid >> 4) * 4;
    v2f acc[4][2] = {};
    for (int kt = 0; kt < 8; ++kt) {
        if (kt) __syncthreads();
        for (int l = tid; l < 64 * 16; l += 256) {
            int r = l >> 4, c4 = (l & 15) * 4;
            int rloc = rt * 64 + r;
            int grow = ((rloc >> 8) * TT) + pp * 256 + (rloc & 255);
            float4 v = *(const float4*)&x[grow * DD + kt * 64 + c4];
            al[(c4 + 0) * 68 + r] = v.x; al[(c4 + 1) * 68 + r] = v.y;
            al[(c4 + 2) * 68 + r] = v.z; al[(c4 + 3) * 68 + r] = v.w;
            float4 u = *(const float4*)&a[(pp * 256 + st * 64 + r) * DD + kt * 64 + c4];
            bl[(c4 + 0) * 68 + r] = u.x; bl[(c4 + 1) * 68 + r] = u.y;
            bl[(c4 + 2) * 68 + r] = u.z; bl[(c4 + 3) * 68 + r] = u.w;
        }
        __syncthreads();
        for (int kk = 0; kk < 64; ++kk) {
            float4 a4 = *(const float4*)&al[kk * 68 + r0];
            float4 b4 = *(const float4*)&bl[kk * 68 + c0];
            v2f blo = {b4.x, b4.y}, bhi = {b4.z, b4.w};
            float af[4] = {a4.x, a4.y, a4.z, a4.w};
#pragma unroll
            for (int q = 0; q < 4; ++q) { acc[q][0] += af[q] * blo; acc[q][1] += af[q] * bhi; }
        }
    }
#pragma unroll
    for (int q = 0; q < 4; ++q) {
        int rloc = rt * 64 + r0 + q;
        float4 v = make_float4(acc[q][0][0], acc[q][0][1], acc[q][1][0], acc[q][1][1]);
        *(float4*)&S[(pp * 2048 + rloc) * 256 + st * 64 + c0] = v;
    }
}

// out[row][i] += LR * sum_{s<tloc} S[p][rloc][s] * cu[p*256+s][i]
__global__ __launch_bounds__(256) void tm_apply(const float* __restrict__ S, const float* __restrict__ cu,
                                                float* __restrict__ out) {
    __shared__ float al[64 * 68];
    __shared__ float bl[64 * 68];
    int bid = blockIdx.x;
    int it = bid & 7, rt = (bid >> 3) & 31, pp = bid >> 8;
    int tid = threadIdx.x;
    int c0 = (tid & 15) * 4, r0 = (tid >> 4) * 4;
    v2f acc[4][2] = {};
    for (int kt = 0; kt < 4; ++kt) {
        if (kt) __syncthreads();
        for (int l = tid; l < 64 * 16; l += 256) {
            int r = l >> 4, c4 = (l & 15) * 4;
            int rloc = rt * 64 + r;
            int tq = rloc & 255;
            float4 v = *(const float4*)&S[(pp * 2048 + rloc) * 256 + kt * 64 + c4];
            int sb = kt * 64 + c4;
            al[(c4 + 0) * 68 + r] = (sb + 0 < tq) ? v.x : 0.f;
            al[(c4 + 1) * 68 + r] = (sb + 1 < tq) ? v.y : 0.f;
            al[(c4 + 2) * 68 + r] = (sb + 2 < tq) ? v.z : 0.f;
            al[(c4 + 3) * 68 + r] = (sb + 3 < tq) ? v.w : 0.f;
            float4 u = *(const float4*)&cu[(pp * 256 + kt * 64 + r) * DD + it * 64 + c4];
            *(float4*)&bl[r * 68 + c4] = u;   // [k][i] layout, aligned b128 write
        }
        __syncthreads();
        for (int kk = 0; kk < 64; ++kk) {
            float4 a4 = *(const float4*)&al[kk * 68 + r0];
            float4 b4 = *(const float4*)&bl[kk * 68 + c0];
            v2f blo = {b4.x, b4.y}, bhi = {b4.z, b4.w};
            float af[4] = {a4.x, a4.y, a4.z, a4.w};
#pragma unroll
            for (int q = 0; q < 4; ++q) { acc[q][0] += af[q] * blo; acc[q][1] += af[q] * bhi; }
        }
    }
#pragma unroll
    for (int q = 0; q < 4; ++q) {
        int rloc = rt * 64 + r0 + q;
        int grow = ((rloc >> 8) * TT) + pp * 256 + (rloc & 255);
        float4 cur = *(float4*)&out[grow * DD + it * 64 + c0];
        cur.x += LRF * acc[q][0][0]; cur.y += LRF * acc[q][0][1];
        cur.z += LRF * acc[q][1][0]; cur.w += LRF * acc[q][1][1];
        *(float4*)&out[grow * DD + it * 64 + c0] = cur;
    }
}

// out[row][i] *= sigmoid(x[row] . gate_w[i] + gate_b[i])
__global__ __launch_bounds__(256) void tm_gate(const float* __restrict__ x, const float* __restrict__ gw,
                                               const float* __restrict__ gb, float* __restrict__ out) {
    __shared__ float al[64 * 68];
    __shared__ float bl[64 * 68];
    int bid = blockIdx.x;
    int it = bid & 7, rt = bid >> 3;
    int tid = threadIdx.x;
    int c0 = (tid & 15) * 4, r0 = (tid >> 4) * 4;
    v2f acc[4][2] = {};
    for (int kt = 0; kt < 8; ++kt) {
        if (kt) __syncthreads();
        for (int l = tid; l < 64 * 16; l += 256) {
            int r = l >> 4, c4 = (l & 15) * 4;
            int grow = rt * 64 + r;
            float4 v = *(const float4*)&x[grow * DD + kt * 64 + c4];
            al[(c4 + 0) * 68 + r] = v.x; al[(c4 + 1) * 68 + r] = v.y;
            al[(c4 + 2) * 68 + r] = v.z; al[(c4 + 3) * 68 + r] = v.w;
            float4 u = *(const float4*)&gw[(it * 64 + r) * DD + kt * 64 + c4];
            bl[(c4 + 0) * 68 + r] = u.x; bl[(c4 + 1) * 68 + r] = u.y;
            bl[(c4 + 2) * 68 + r] = u.z; bl[(c4 + 3) * 68 + r] = u.w;
        }
        __syncthreads();
        for (int kk = 0; kk < 64; ++kk) {
            float4 a4 = *(const float4*)&al[kk * 68 + r0];
            float4 b4 = *(const float4*)&bl[kk * 68 + c0];
            v2f blo = {b4.x, b4.y}, bhi = {b4.z, b4.w};
            float af[4] = {a4.x, a4.y, a4.z, a4.w};
#pragma unroll
            for (int q = 0; q < 4; ++q) { acc[q][0] += af[q] * blo; acc[q][1] += af[q] * bhi; }
        }
    }
#pragma unroll
    for (int q = 0; q < 4; ++q) {
        int grow = rt * 64 + r0 + q;
        float4 cur = *(float4*)&out[grow * DD + it * 64 + c0];
        float z0 = acc[q][0][0] + gb[it * 64 + c0 + 0];
        float z1 = acc[q][0][1] + gb[it * 64 + c0 + 1];
        float z2 = acc[q][1][0] + gb[it * 64 + c0 + 2];
        float z3 = acc[q][1][1] + gb[it * 64 + c0 + 3];
        cur.x *= 1.f / (1.f + expf(-z0));
        cur.y *= 1.f / (1.f + expf(-z1));
        cur.z *= 1.f / (1.f + expf(-z2));
        cur.w *= 1.f / (1.f + expf(-z3));
        *(float4*)&out[grow * DD + it * 64 + c0] = cur;
    }
}

extern "C" void kernel_launch(void* const* d_in, const int* in_sizes, int n_in,
                              void* d_out, int out_size, void* d_ws, size_t ws_size,
                              hipStream_t stream) {
    const float* x   = (const float*)d_in[0];
    const float* Wc0 = (const float*)d_in[1];
    const float* Wb  = (const float*)d_in[2];
    const float* gw  = (const float*)d_in[3];
    const float* gb  = (const float*)d_in[4];
    float* out  = (float*)d_out;
    float* outW = out + BB * TT * DD;

    float* ws = (float*)d_ws;
    float* A  = ws + OFF_A;
    float* CU = ws + OFF_CU;
    float* G  = ws + OFF_G;
    float* P  = ws + OFF_P;
    float* W  = ws + OFF_W;
    float* WS = ws + OFF_WS;
    float* S  = ws + OFF_S;

    tm_mean<<<(TT * DD) / 256, 256, 0, stream>>>(x, A);
    tm_init<<<(DD * DD) / 256, 256, 0, stream>>>(Wb, Wc0, W, WS);
    tm_gram<<<256, 256, 0, stream>>>(A, G);
    tm_P<<<32, 256, 0, stream>>>(A, W, P, 0);

    for (int p = 0; p < 16; ++p) {
        tm_sc<<<1, 512, 0, stream>>>(G, P, CU, p);
        if (p < 15) {
            tm_wupd<<<(DD * DD) / 256, 256, 0, stream>>>(A, CU, W, WS, Wb, outW, p, p + 1, 0);
            tm_P<<<32, 256, 0, stream>>>(A, W, P, p + 1);
        }
    }
    tm_wupd<<<(DD * DD) / 256, 256, 0, stream>>>(A, CU, W, WS, Wb, outW, 15, -1, 1);

    tm_mem<<<16 * 256, 256, 0, stream>>>(x, WS, out);
    tm_score<<<16 * 128, 256, 0, stream>>>(x, A, S);
    tm_apply<<<16 * 256, 256, 0, stream>>>(S, CU, out);
    tm_gate<<<512 * 8, 256, 0, stream>>>(x, gw, gb, out);
}

// Round 4
// 15868.506 us; speedup vs baseline: 1.4490x; 1.4490x over previous
//
#include <hip/hip_runtime.h>
#include <math.h>

#define BB 8
#define TT 4096
#define DD 512
constexpr float LRF = 0.01f;

typedef float v2f __attribute__((ext_vector_type(2)));

// ---------------- workspace layout (floats) ----------------
// A  : [4096][512]     mean of x over batch
// CU : [4096][512]     c_s * u_s
// G  : [16][256][256]  per-superchunk Gram of A
// P  : [256][512]      A_sc - A_sc @ W(p)^T (RMW'd in tm_sc by forward corrections)
// W  : [512][512]      running W_base + W_c
// WS : [16][512][512]  W snapshots at t = 256*p
// S  : [16][2048][256] attention scores
#define OFF_A  0
#define OFF_CU 2097152
#define OFF_G  4194304
#define OFF_P  5242880
#define OFF_W  5406720
#define OFF_WS 5668864
#define OFF_S  9863168

__global__ void tm_mean(const float* __restrict__ x, float* __restrict__ a) {
    int idx = blockIdx.x * 256 + threadIdx.x;
    float s = 0.f;
#pragma unroll
    for (int b = 0; b < BB; ++b) s += x[b * (TT * DD) + idx];
    a[idx] = s * 0.125f;
}

__global__ void tm_init(const float* __restrict__ wb, const float* __restrict__ wc,
                        float* __restrict__ W, float* __restrict__ Wsnap) {
    int idx = blockIdx.x * 256 + threadIdx.x;
    float v = wb[idx] + wc[idx];
    W[idx] = v;
    Wsnap[idx] = v;
}

// G[p][s][t] = a_{p*256+s} . a_{p*256+t}; grid 256
__global__ __launch_bounds__(256) void tm_gram(const float* __restrict__ a, float* __restrict__ G) {
    __shared__ float sl[64 * 65];
    __shared__ float tl[64 * 65];
    int bid = blockIdx.x;
    int p = bid >> 4, ts = (bid >> 2) & 3, tt = bid & 3;
    int tid = threadIdx.x;
    int c0 = (tid & 15) * 4, r0 = (tid >> 4) * 4;
    float acc[4][4] = {};
    for (int kt = 0; kt < 8; ++kt) {
        if (kt) __syncthreads();
        for (int l = tid; l < 64 * 16; l += 256) {
            int r = l >> 4, c4 = (l & 15) * 4;
            float4 v = *(const float4*)&a[(p * 256 + ts * 64 + r) * DD + kt * 64 + c4];
            sl[r * 65 + c4] = v.x; sl[r * 65 + c4 + 1] = v.y;
            sl[r * 65 + c4 + 2] = v.z; sl[r * 65 + c4 + 3] = v.w;
            float4 u = *(const float4*)&a[(p * 256 + tt * 64 + r) * DD + kt * 64 + c4];
            tl[r * 65 + c4] = u.x; tl[r * 65 + c4 + 1] = u.y;
            tl[r * 65 + c4 + 2] = u.z; tl[r * 65 + c4 + 3] = u.w;
        }
        __syncthreads();
        for (int kk = 0; kk < 64; ++kk) {
            float as[4], at[4];
#pragma unroll
            for (int q = 0; q < 4; ++q) { as[q] = sl[(r0 + q) * 65 + kk]; at[q] = tl[(c0 + q) * 65 + kk]; }
#pragma unroll
            for (int q = 0; q < 4; ++q)
#pragma unroll
                for (int w2 = 0; w2 < 4; ++w2) acc[q][w2] += as[q] * at[w2];
        }
    }
#pragma unroll
    for (int q = 0; q < 4; ++q) {
        float4 v = make_float4(acc[q][0], acc[q][1], acc[q][2], acc[q][3]);
        *(float4*)&G[p * 65536 + (ts * 64 + r0 + q) * 256 + tt * 64 + c0] = v;
    }
}

// P[t][i] = a[p*256+t][i] - sum_j W[i][j] a[p*256+t][j]; grid 32
__global__ __launch_bounds__(256) void tm_P(const float* __restrict__ a, const float* __restrict__ W,
                                            float* __restrict__ P, int p) {
    __shared__ float al[64 * 65];
    __shared__ float wl[64 * 65];
    int bid = blockIdx.x;
    int bt = bid & 3, bi = bid >> 2;
    int tid = threadIdx.x;
    int c0 = (tid & 15) * 4, r0 = (tid >> 4) * 4;
    float acc[4][4] = {};
    for (int kt = 0; kt < 8; ++kt) {
        if (kt) __syncthreads();
        for (int l = tid; l < 64 * 16; l += 256) {
            int r = l >> 4, c4 = (l & 15) * 4;
            float4 v = *(const float4*)&a[(p * 256 + bt * 64 + r) * DD + kt * 64 + c4];
            al[r * 65 + c4] = v.x; al[r * 65 + c4 + 1] = v.y;
            al[r * 65 + c4 + 2] = v.z; al[r * 65 + c4 + 3] = v.w;
            float4 u = *(const float4*)&W[(bi * 64 + r) * DD + kt * 64 + c4];
            wl[r * 65 + c4] = u.x; wl[r * 65 + c4 + 1] = u.y;
            wl[r * 65 + c4 + 2] = u.z; wl[r * 65 + c4 + 3] = u.w;
        }
        __syncthreads();
        for (int kk = 0; kk < 64; ++kk) {
            float af[4], bf[4];
#pragma unroll
            for (int q = 0; q < 4; ++q) { af[q] = al[(r0 + q) * 65 + kk]; bf[q] = wl[(c0 + q) * 65 + kk]; }
#pragma unroll
            for (int q = 0; q < 4; ++q)
#pragma unroll
                for (int w2 = 0; w2 < 4; ++w2) acc[q][w2] += af[q] * bf[w2];
        }
    }
#pragma unroll
    for (int q = 0; q < 4; ++q) {
        float4 av = *(const float4*)&a[(p * 256 + bt * 64 + r0 + q) * DD + bi * 64 + c0];
        float4 v = make_float4(av.x - acc[q][0], av.y - acc[q][1],
                               av.z - acc[q][2], av.w - acc[q][3]);
        *(float4*)&P[(bt * 64 + r0 + q) * DD + bi * 64 + c0] = v;
    }
}

// ---- fused per-superchunk serial kernel: 1 block, 512 threads ----
// Per chunk j: (a) scan (threads<256 active, 2 dims each, Gram diag block in LDS),
// (b) corrections to future chunks as an 8-wave tile GEMM (g from LDS broadcast,
// y streamed from global cu, P RMW'd in place).
__global__ __launch_bounds__(512) void tm_sc(const float* __restrict__ G,
                                             float* __restrict__ P,
                                             float* __restrict__ cu, int p) {
    __shared__ float gl[64 * 64];
    __shared__ float part[2][4];
    int tid = threadIdx.x;
    int lane = tid & 63;
    int wid = tid >> 6;
    const float* Gp = G + p * 65536;
    float* cup = cu + p * 256 * DD;

    for (int j = 0; j < 4; ++j) {
        // stage diag Gram block (j,j)
        __syncthreads();
        for (int l = tid; l < 64 * 16; l += 512) {
            int r = l >> 4, c4 = (l & 15) * 4;
            *(float4*)&gl[r * 64 + c4] = *(const float4*)&Gp[(j * 64 + r) * 256 + j * 64 + c4];
        }
        __syncthreads();

        // ---- scan chunk j ----
        float b0[64], b1[64];
        if (tid < 256) {
#pragma unroll
            for (int t = 0; t < 64; ++t) {
                b0[t] = P[(j * 64 + t) * DD + tid];
                b1[t] = P[(j * 64 + t) * DD + tid + 256];
            }
        }
        float* cuj = cup + (j * 64) * DD;
#pragma unroll
        for (int s = 0; s < 64; ++s) {
            if (tid < 256) {
                float u0 = b0[s], u1 = b1[s];
                float v = u0 * u0 + u1 * u1;
#pragma unroll
                for (int off = 32; off > 0; off >>= 1) v += __shfl_xor(v, off, 64);
                if (lane == 0) part[s & 1][wid] = v;
            }
            __syncthreads();
            if (tid < 256) {
                float u0 = b0[s], u1 = b1[s];
                float n2u = part[s & 1][0] + part[s & 1][1] + part[s & 1][2] + part[s & 1][3];
                float n2 = n2u * gl[s * 64 + s];                      // ||u||^2 * ||a||^2
                float cs = (n2 > 0.25f) ? 0.5f * rsqrtf(n2) : 1.0f;  // min(1, CLIP/n)
                cuj[s * DD + tid] = cs * u0;
                cuj[s * DD + tid + 256] = cs * u1;
                float w0 = (LRF * cs) * u0, w1 = (LRF * cs) * u1;
                int t0 = s + 1;
#pragma unroll
                for (; t0 < 64 && (t0 & 3); ++t0) {
                    float g = gl[s * 64 + t0];
                    b0[t0] -= g * w0; b1[t0] -= g * w1;
                }
#pragma unroll
                for (; t0 < 64; t0 += 4) {
                    float4 g4 = *(const float4*)&gl[s * 64 + t0];
                    b0[t0]     -= g4.x * w0; b1[t0]     -= g4.x * w1;
                    b0[t0 + 1] -= g4.y * w0; b1[t0 + 1] -= g4.y * w1;
                    b0[t0 + 2] -= g4.z * w0; b1[t0 + 2] -= g4.z * w1;
                    b0[t0 + 3] -= g4.w * w0; b1[t0 + 3] -= g4.w * w1;
                }
            }
        }
        __threadfence_block();   // make cu stores visible to all waves

        // ---- corrections to future chunks: P[jf] -= LR * g(j,jf)^T @ y(j) ----
        int tq = tid >> 6;        // wave id -> 8 t-rows
        int dg = tid & 63;        // 8 d-cols
        for (int jf = j + 1; jf < 4; ++jf) {
            __syncthreads();
            for (int l = tid; l < 64 * 16; l += 512) {
                int r = l >> 4, c4 = (l & 15) * 4;
                *(float4*)&gl[r * 64 + c4] = *(const float4*)&Gp[(j * 64 + r) * 256 + jf * 64 + c4];
            }
            __syncthreads();
            float acc[8][8] = {};
            for (int kk = 0; kk < 64; ++kk) {
                float4 ga = *(const float4*)&gl[kk * 64 + tq * 8];       // broadcast within wave
                float4 gb = *(const float4*)&gl[kk * 64 + tq * 8 + 4];
                float4 y0 = *(const float4*)&cuj[kk * DD + dg * 8];
                float4 y1 = *(const float4*)&cuj[kk * DD + dg * 8 + 4];
                float gv[8] = {ga.x, ga.y, ga.z, ga.w, gb.x, gb.y, gb.z, gb.w};
                float yv[8] = {y0.x, y0.y, y0.z, y0.w, y1.x, y1.y, y1.z, y1.w};
#pragma unroll
                for (int i = 0; i < 8; ++i)
#pragma unroll
                    for (int q = 0; q < 8; ++q) acc[i][q] += gv[i] * yv[q];
            }
#pragma unroll
            for (int i = 0; i < 8; ++i) {
                float* prow = P + (jf * 64 + tq * 8 + i) * DD + dg * 8;
                float4 p0 = *(const float4*)&prow[0];
                float4 p1 = *(const float4*)&prow[4];
                p0.x -= LRF * acc[i][0]; p0.y -= LRF * acc[i][1];
                p0.z -= LRF * acc[i][2]; p0.w -= LRF * acc[i][3];
                p1.x -= LRF * acc[i][4]; p1.y -= LRF * acc[i][5];
                p1.z -= LRF * acc[i][6]; p1.w -= LRF * acc[i][7];
                *(float4*)&prow[0] = p0;
                *(float4*)&prow[4] = p1;
            }
        }
    }
}

// W += LR * sum_{r in sc p} cu_r (x) a_r; optional snapshot / final output
__global__ void tm_wupd(const float* __restrict__ a, const float* __restrict__ cu,
                        float* __restrict__ W, float* __restrict__ Wsnap,
                        const float* __restrict__ wb, float* __restrict__ outW,
                        int p, int snap_p, int is_final) {
    int idx = blockIdx.x * 256 + threadIdx.x;
    int i = idx >> 9, jj = idx & 511;
    const float* cb = cu + p * 256 * DD + i;
    const float* ab = a + p * 256 * DD + jj;
    float s = 0.f;
#pragma unroll 8
    for (int r = 0; r < 256; ++r) s += cb[r * DD] * ab[r * DD];
    float w = W[idx] + LRF * s;
    W[idx] = w;
    if (snap_p >= 0) Wsnap[snap_p * DD * DD + idx] = w;
    if (is_final) outW[idx] = w - wb[idx];
}

// ---------------- phase 3 (parallel output), transposed-LDS b128 fragments ----------------

__global__ __launch_bounds__(256) void tm_mem(const float* __restrict__ x, const float* __restrict__ Wsnap,
                                              float* __restrict__ out) {
    __shared__ float al[64 * 68];
    __shared__ float bl[64 * 68];
    int bid = blockIdx.x;
    int pp = bid >> 8, rem = bid & 255, rt = rem >> 3, it = rem & 7;
    int tid = threadIdx.x;
    int c0 = (tid & 15) * 4, r0 = (tid >> 4) * 4;
    const float* Wp = Wsnap + pp * DD * DD;
    v2f acc[4][2] = {};
    for (int kt = 0; kt < 8; ++kt) {
        if (kt) __syncthreads();
        for (int l = tid; l < 64 * 16; l += 256) {
            int r = l >> 4, c4 = (l & 15) * 4;
            int rloc = rt * 64 + r;
            int grow = ((rloc >> 8) * TT) + pp * 256 + (rloc & 255);
            float4 v = *(const float4*)&x[grow * DD + kt * 64 + c4];
            al[(c4 + 0) * 68 + r] = v.x; al[(c4 + 1) * 68 + r] = v.y;
            al[(c4 + 2) * 68 + r] = v.z; al[(c4 + 3) * 68 + r] = v.w;
            float4 u = *(const float4*)&Wp[(it * 64 + r) * DD + kt * 64 + c4];
            bl[(c4 + 0) * 68 + r] = u.x; bl[(c4 + 1) * 68 + r] = u.y;
            bl[(c4 + 2) * 68 + r] = u.z; bl[(c4 + 3) * 68 + r] = u.w;
        }
        __syncthreads();
        for (int kk = 0; kk < 64; ++kk) {
            float4 a4 = *(const float4*)&al[kk * 68 + r0];
            float4 b4 = *(const float4*)&bl[kk * 68 + c0];
            v2f blo = {b4.x, b4.y}, bhi = {b4.z, b4.w};
            float af[4] = {a4.x, a4.y, a4.z, a4.w};
#pragma unroll
            for (int q = 0; q < 4; ++q) { acc[q][0] += af[q] * blo; acc[q][1] += af[q] * bhi; }
        }
    }
#pragma unroll
    for (int q = 0; q < 4; ++q) {
        int rloc = rt * 64 + r0 + q;
        int grow = ((rloc >> 8) * TT) + pp * 256 + (rloc & 255);
        float4 v = make_float4(acc[q][0][0], acc[q][0][1], acc[q][1][0], acc[q][1][1]);
        *(float4*)&out[grow * DD + it * 64 + c0] = v;
    }
}

__global__ __launch_bounds__(256) void tm_score(const float* __restrict__ x, const float* __restrict__ a,
                                                float* __restrict__ S) {
    __shared__ float al[64 * 68];
    __shared__ float bl[64 * 68];
    int bid = blockIdx.x;
    int st = bid & 3, rt = (bid >> 2) & 31, pp = bid >> 7;
    int tid = threadIdx.x;
    int c0 = (tid & 15) * 4, r0 = (tid >> 4) * 4;
    v2f acc[4][2] = {};
    for (int kt = 0; kt < 8; ++kt) {
        if (kt) __syncthreads();
        for (int l = tid; l < 64 * 16; l += 256) {
            int r = l >> 4, c4 = (l & 15) * 4;
            int rloc = rt * 64 + r;
            int grow = ((rloc >> 8) * TT) + pp * 256 + (rloc & 255);
            float4 v = *(const float4*)&x[grow * DD + kt * 64 + c4];
            al[(c4 + 0) * 68 + r] = v.x; al[(c4 + 1) * 68 + r] = v.y;
            al[(c4 + 2) * 68 + r] = v.z; al[(c4 + 3) * 68 + r] = v.w;
            float4 u = *(const float4*)&a[(pp * 256 + st * 64 + r) * DD + kt * 64 + c4];
            bl[(c4 + 0) * 68 + r] = u.x; bl[(c4 + 1) * 68 + r] = u.y;
            bl[(c4 + 2) * 68 + r] = u.z; bl[(c4 + 3) * 68 + r] = u.w;
        }
        __syncthreads();
        for (int kk = 0; kk < 64; ++kk) {
            float4 a4 = *(const float4*)&al[kk * 68 + r0];
            float4 b4 = *(const float4*)&bl[kk * 68 + c0];
            v2f blo = {b4.x, b4.y}, bhi = {b4.z, b4.w};
            float af[4] = {a4.x, a4.y, a4.z, a4.w};
#pragma unroll
            for (int q = 0; q < 4; ++q) { acc[q][0] += af[q] * blo; acc[q][1] += af[q] * bhi; }
        }
    }
#pragma unroll
    for (int q = 0; q < 4; ++q) {
        int rloc = rt * 64 + r0 + q;
        float4 v = make_float4(acc[q][0][0], acc[q][0][1], acc[q][1][0], acc[q][1][1]);
        *(float4*)&S[(pp * 2048 + rloc) * 256 + st * 64 + c0] = v;
    }
}

__global__ __launch_bounds__(256) void tm_apply(const float* __restrict__ S, const float* __restrict__ cu,
                                                float* __restrict__ out) {
    __shared__ float al[64 * 68];
    __shared__ float bl[64 * 68];
    int bid = blockIdx.x;
    int it = bid & 7, rt = (bid >> 3) & 31, pp = bid >> 8;
    int tid = threadIdx.x;
    int c0 = (tid & 15) * 4, r0 = (tid >> 4) * 4;
    v2f acc[4][2] = {};
    for (int kt = 0; kt < 4; ++kt) {
        if (kt) __syncthreads();
        for (int l = tid; l < 64 * 16; l += 256) {
            int r = l >> 4, c4 = (l & 15) * 4;
            int rloc = rt * 64 + r;
            int tq = rloc & 255;
            float4 v = *(const float4*)&S[(pp * 2048 + rloc) * 256 + kt * 64 + c4];
            int sb = kt * 64 + c4;
            al[(c4 + 0) * 68 + r] = (sb + 0 < tq) ? v.x : 0.f;
            al[(c4 + 1) * 68 + r] = (sb + 1 < tq) ? v.y : 0.f;
            al[(c4 + 2) * 68 + r] = (sb + 2 < tq) ? v.z : 0.f;
            al[(c4 + 3) * 68 + r] = (sb + 3 < tq) ? v.w : 0.f;
            float4 u = *(const float4*)&cu[(pp * 256 + kt * 64 + r) * DD + it * 64 + c4];
            *(float4*)&bl[r * 68 + c4] = u;
        }
        __syncthreads();
        for (int kk = 0; kk < 64; ++kk) {
            float4 a4 = *(const float4*)&al[kk * 68 + r0];
            float4 b4 = *(const float4*)&bl[kk * 68 + c0];
            v2f blo = {b4.x, b4.y}, bhi = {b4.z, b4.w};
            float af[4] = {a4.x, a4.y, a4.z, a4.w};
#pragma unroll
            for (int q = 0; q < 4; ++q) { acc[q][0] += af[q] * blo; acc[q][1] += af[q] * bhi; }
        }
    }
#pragma unroll
    for (int q = 0; q < 4; ++q) {
        int rloc = rt * 64 + r0 + q;
        int grow = ((rloc >> 8) * TT) + pp * 256 + (rloc & 255);
        float4 cur = *(float4*)&out[grow * DD + it * 64 + c0];
        cur.x += LRF * acc[q][0][0]; cur.y += LRF * acc[q][0][1];
        cur.z += LRF * acc[q][1][0]; cur.w += LRF * acc[q][1][1];
        *(float4*)&out[grow * DD + it * 64 + c0] = cur;
    }
}

__global__ __launch_bounds__(256) void tm_gate(const float* __restrict__ x, const float* __restrict__ gw,
                                               const float* __restrict__ gb, float* __restrict__ out) {
    __shared__ float al[64 * 68];
    __shared__ float bl[64 * 68];
    int bid = blockIdx.x;
    int it = bid & 7, rt = bid >> 3;
    int tid = threadIdx.x;
    int c0 = (tid & 15) * 4, r0 = (tid >> 4) * 4;
    v2f acc[4][2] = {};
    for (int kt = 0; kt < 8; ++kt) {
        if (kt) __syncthreads();
        for (int l = tid; l < 64 * 16; l += 256) {
            int r = l >> 4, c4 = (l & 15) * 4;
            int grow = rt * 64 + r;
            float4 v = *(const float4*)&x[grow * DD + kt * 64 + c4];
            al[(c4 + 0) * 68 + r] = v.x; al[(c4 + 1) * 68 + r] = v.y;
            al[(c4 + 2) * 68 + r] = v.z; al[(c4 + 3) * 68 + r] = v.w;
            float4 u = *(const float4*)&gw[(it * 64 + r) * DD + kt * 64 + c4];
            bl[(c4 + 0) * 68 + r] = u.x; bl[(c4 + 1) * 68 + r] = u.y;
            bl[(c4 + 2) * 68 + r] = u.z; bl[(c4 + 3) * 68 + r] = u.w;
        }
        __syncthreads();
        for (int kk = 0; kk < 64; ++kk) {
            float4 a4 = *(const float4*)&al[kk * 68 + r0];
            float4 b4 = *(const float4*)&bl[kk * 68 + c0];
            v2f blo = {b4.x, b4.y}, bhi = {b4.z, b4.w};
            float af[4] = {a4.x, a4.y, a4.z, a4.w};
#pragma unroll
            for (int q = 0; q < 4; ++q) { acc[q][0] += af[q] * blo; acc[q][1] += af[q] * bhi; }
        }
    }
#pragma unroll
    for (int q = 0; q < 4; ++q) {
        int grow = rt * 64 + r0 + q;
        float4 cur = *(float4*)&out[grow * DD + it * 64 + c0];
        float z0 = acc[q][0][0] + gb[it * 64 + c0 + 0];
        float z1 = acc[q][0][1] + gb[it * 64 + c0 + 1];
        float z2 = acc[q][1][0] + gb[it * 64 + c0 + 2];
        float z3 = acc[q][1][1] + gb[it * 64 + c0 + 3];
        cur.x *= 1.f / (1.f + expf(-z0));
        cur.y *= 1.f / (1.f + expf(-z1));
        cur.z *= 1.f / (1.f + expf(-z2));
        cur.w *= 1.f / (1.f + expf(-z3));
        *(float4*)&out[grow * DD + it * 64 + c0] = cur;
    }
}

extern "C" void kernel_launch(void* const* d_in, const int* in_sizes, int n_in,
                              void* d_out, int out_size, void* d_ws, size_t ws_size,
                              hipStream_t stream) {
    const float* x   = (const float*)d_in[0];
    const float* Wc0 = (const float*)d_in[1];
    const float* Wb  = (const float*)d_in[2];
    const float* gw  = (const float*)d_in[3];
    const float* gb  = (const float*)d_in[4];
    float* out  = (float*)d_out;
    float* outW = out + BB * TT * DD;

    float* ws = (float*)d_ws;
    float* A  = ws + OFF_A;
    float* CU = ws + OFF_CU;
    float* G  = ws + OFF_G;
    float* P  = ws + OFF_P;
    float* W  = ws + OFF_W;
    float* WS = ws + OFF_WS;
    float* S  = ws + OFF_S;

    tm_mean<<<(TT * DD) / 256, 256, 0, stream>>>(x, A);
    tm_init<<<(DD * DD) / 256, 256, 0, stream>>>(Wb, Wc0, W, WS);
    tm_gram<<<256, 256, 0, stream>>>(A, G);
    tm_P<<<32, 256, 0, stream>>>(A, W, P, 0);

    for (int p = 0; p < 16; ++p) {
        tm_sc<<<1, 512, 0, stream>>>(G, P, CU, p);
        if (p < 15) {
            tm_wupd<<<(DD * DD) / 256, 256, 0, stream>>>(A, CU, W, WS, Wb, outW, p, p + 1, 0);
            tm_P<<<32, 256, 0, stream>>>(A, W, P, p + 1);
        }
    }
    tm_wupd<<<(DD * DD) / 256, 256, 0, stream>>>(A, CU, W, WS, Wb, outW, 15, -1, 1);

    tm_mem<<<16 * 256, 256, 0, stream>>>(x, WS, out);
    tm_score<<<16 * 128, 256, 0, stream>>>(x, A, S);
    tm_apply<<<16 * 256, 256, 0, stream>>>(S, CU, out);
    tm_gate<<<512 * 8, 256, 0, stream>>>(x, gw, gb, out);
}